// Round 1
// 690.022 us; speedup vs baseline: 1.0037x; 1.0037x over previous
//
#include <hip/hip_runtime.h>
#include <hip/hip_bf16.h>
#include <hip/hip_cooperative_groups.h>

namespace cg = cooperative_groups;

#define NF 40960
#define MD 256
#define BATCH 2048
#define NBLK 1024              // coop grid: 2 positions per block
#define CAP 512
#define NTILE ((NF / 64) * (MD / 64))   // 2560 64x64 tiles

typedef float vf4 __attribute__((ext_vector_type(4)));

__device__ __forceinline__ float clip01(float v) {
    return fminf(fmaxf(v, 0.0f), 1.0f);
}

// ===========================================================================
// NEW coop path: 2 positions/block, deep-batched scan + gather (16 loads/BB).
// ===========================================================================
struct Scan2 {
    int idx[4][CAP];       // lists: 0=p0W 1=p0B 2=p1W 3=p1B   (8 KB)
    int n[4];
    float xsh[512];
    float red[32][9];
    float ysh[32], zsh[32];
};
union Smem2 {
    float tile[64][65];    // 16.64 KB transpose phase
    Scan2 s;               // ~11.6 KB scan/MLP phase
};

__device__ __forceinline__ void mlp_tail2(Scan2& s, int t, int pos,
    float accW, float accB,
    const float* __restrict__ stm,
    const float* __restrict__ l1_w, const float* __restrict__ l1_b,
    const float* __restrict__ l2_w, const float* __restrict__ l2_b,
    const float* __restrict__ l3_w, const float* __restrict__ l3_b,
    float* __restrict__ out)
{
    const float sv = stm[pos];
    s.xsh[t]       = clip01(sv * accW + (1.0f - sv) * accB);
    s.xsh[256 + t] = clip01(sv * accB + (1.0f - sv) * accW);
    __syncthreads();
    {   // L1: n = t&31 (broadcast reads), chunk c = t>>5
        const int n = t & 31;
        const int c = t >> 5;
        const float* w1 = l1_w + (size_t)n * 512 + c * 64;
        const float* xx = s.xsh + c * 64;
        float p = 0.0f;
        #pragma unroll
        for (int j = 0; j < 64; ++j) p += xx[j] * w1[j];
        s.red[n][c] = p;
    }
    __syncthreads();
    if (t < 32) {
        float v = l1_b[t];
        #pragma unroll
        for (int c = 0; c < 8; ++c) v += s.red[t][c];
        s.ysh[t] = clip01(v);
    }
    __syncthreads();
    if (t < 32) {
        float v = l2_b[t];
        const float* w2 = l2_w + t * 32;
        #pragma unroll
        for (int j = 0; j < 32; ++j) v += s.ysh[j] * w2[j];
        s.zsh[t] = clip01(v);
    }
    __syncthreads();
    if (t == 0) {
        float v = l3_b[0];
        #pragma unroll
        for (int j = 0; j < 32; ++j) v += s.zsh[j] * l3_w[j];
        out[pos] = (clip01(v) - 0.5f) * 20000.0f;
    }
    __syncthreads();   // order tail(p0) reads vs tail(p1) writes of red/ysh/zsh
}

__global__ __launch_bounds__(256, 4) void nnue_coop2(
    const float* __restrict__ wf, const float* __restrict__ bfeat,
    const float* __restrict__ stm, const float* __restrict__ ft_w,
    const float* __restrict__ ft_b,
    const float* __restrict__ l1_w, const float* __restrict__ l1_b,
    const float* __restrict__ l2_w, const float* __restrict__ l2_b,
    const float* __restrict__ l3_w, const float* __restrict__ l3_b,
    float* __restrict__ out, float* __restrict__ ftT)
{
    __shared__ Smem2 u;
    const int b = blockIdx.x;
    const int t = threadIdx.x;

    // ---- phase A: this block's transpose share (2 or 3 tiles)
    for (int tl = b; tl < NTILE; tl += NBLK) {
        const int f0 = (tl % (NF / 64)) * 64;
        const int m0 = (tl / (NF / 64)) * 64;
        const int tx = t & 63;
        const int ty = t >> 6;
        #pragma unroll
        for (int r = ty; r < 64; r += 4)
            u.tile[r][tx] = ft_w[(size_t)(m0 + r) * NF + f0 + tx];
        __syncthreads();
        #pragma unroll
        for (int r = ty; r < 64; r += 4)
            ftT[(size_t)(f0 + r) * MD + m0 + tx] = u.tile[tx][r];
        __syncthreads();
    }
    if (b == 0) ftT[(size_t)NF * MD + t] = 0.0f;   // zero pad row (index NF)

    // ---- phase B: scan TWO positions (4 streams), 16 loads in flight per BB
    const int p0 = b;
    const int p1 = b + NBLK;
    if (t < 4) u.s.n[t] = 0;
    __syncthreads();
    {
        const vf4* sp[4] = {
            (const vf4*)(wf    + (size_t)p0 * NF),
            (const vf4*)(bfeat + (size_t)p0 * NF),
            (const vf4*)(wf    + (size_t)p1 * NF),
            (const vf4*)(bfeat + (size_t)p1 * NF) };
        // NF/4 = 10240 vf4 per stream; per thread 40 per stream; 10 superiters x 4
        for (int k = 0; k < 10; ++k) {
            vf4 r[16];
            #pragma unroll
            for (int l = 0; l < 4; ++l)
                #pragma unroll
                for (int q = 0; q < 4; ++q)
                    r[l * 4 + q] = __builtin_nontemporal_load(
                        sp[l] + (t + (k * 4 + q) * 256));
            #pragma unroll
            for (int l = 0; l < 4; ++l)
                #pragma unroll
                for (int q = 0; q < 4; ++q) {
                    vf4 v = r[l * 4 + q];
                    // features are exactly 0/1 -> sum nonzero iff any nonzero
                    if (__builtin_expect(v.x + v.y + v.z + v.w != 0.0f, 0)) {
                        const int fb = (t + (k * 4 + q) * 256) * 4;
                        if (v.x != 0.0f) { int p = atomicAdd(&u.s.n[l], 1); if (p < CAP) u.s.idx[l][p] = fb;     }
                        if (v.y != 0.0f) { int p = atomicAdd(&u.s.n[l], 1); if (p < CAP) u.s.idx[l][p] = fb + 1; }
                        if (v.z != 0.0f) { int p = atomicAdd(&u.s.n[l], 1); if (p < CAP) u.s.idx[l][p] = fb + 2; }
                        if (v.w != 0.0f) { int p = atomicAdd(&u.s.n[l], 1); if (p < CAP) u.s.idx[l][p] = fb + 3; }
                    }
                }
        }
    }
    __syncthreads();

    // ---- pad all 4 lists to common multiple-of-4 length m (dummy -> zero row NF)
    const int c0 = min(u.s.n[0], CAP), c1 = min(u.s.n[1], CAP);
    const int c2 = min(u.s.n[2], CAP), c3 = min(u.s.n[3], CAP);
    const int m = (max(max(c0, c1), max(c2, c3)) + 3) & ~3;   // <= CAP
    if (t < 4) {
        const int cl = min(u.s.n[t], CAP);
        for (int k2 = cl; k2 < m; ++k2) u.s.idx[t][k2] = NF;
    }

    // ---- phase C: wait for all transpose shares (+ pad row) grid-wide
    __threadfence();
    cg::this_grid().sync();
    __threadfence();

    // ---- phase D: batched gather: 16 independent loads per iteration
    const float bias = ft_b[t];
    float a0 = 0.0f, a1 = 0.0f, a2 = 0.0f, a3 = 0.0f;
    for (int j = 0; j < m; j += 4) {
        float v[16];
        #pragma unroll
        for (int l = 0; l < 4; ++l)
            #pragma unroll
            for (int q = 0; q < 4; ++q)
                v[l * 4 + q] = ftT[(size_t)u.s.idx[l][j + q] * MD + t];
        a0 += (v[0]  + v[1])  + (v[2]  + v[3]);
        a1 += (v[4]  + v[5])  + (v[6]  + v[7]);
        a2 += (v[8]  + v[9])  + (v[10] + v[11]);
        a3 += (v[12] + v[13]) + (v[14] + v[15]);
    }

    // ---- phase E: per-position MLP tails
    mlp_tail2(u.s, t, p0, bias + a0, bias + a1, stm,
              l1_w, l1_b, l2_w, l2_b, l3_w, l3_b, out);
    mlp_tail2(u.s, t, p1, bias + a2, bias + a3, stm,
              l1_w, l1_b, l2_w, l2_b, l3_w, l3_b, out);
}

// ===========================================================================
// Fallback path (verified R1): separate transpose + monolithic kernel.
// ===========================================================================
struct ScanSmem {
    int idxW[CAP], idxB[CAP];
    int nW, nB;
    float xsh[512];
    float red[32][9];
    float ysh[32], zsh[32];
};
union Smem {
    float tile[64][65];
    ScanSmem s;
};

__device__ __forceinline__ void scan_pos(ScanSmem& s, int t, int pos,
    const float* __restrict__ wf, const float* __restrict__ bfeat)
{
    if (t == 0) { s.nW = 0; s.nB = 0; }
    __syncthreads();
    const vf4* wf4 = (const vf4*)(wf + (size_t)pos * NF);
    const vf4* bf4 = (const vf4*)(bfeat + (size_t)pos * NF);
    #pragma unroll 4
    for (int i = t; i < NF / 4; i += 256) {
        vf4 v = __builtin_nontemporal_load(wf4 + i);
        if (v.x + v.y + v.z + v.w != 0.0f) {
            if (v.x != 0.0f) { int p = atomicAdd(&s.nW, 1); if (p < CAP) s.idxW[p] = 4 * i;     }
            if (v.y != 0.0f) { int p = atomicAdd(&s.nW, 1); if (p < CAP) s.idxW[p] = 4 * i + 1; }
            if (v.z != 0.0f) { int p = atomicAdd(&s.nW, 1); if (p < CAP) s.idxW[p] = 4 * i + 2; }
            if (v.w != 0.0f) { int p = atomicAdd(&s.nW, 1); if (p < CAP) s.idxW[p] = 4 * i + 3; }
        }
        vf4 uu = __builtin_nontemporal_load(bf4 + i);
        if (uu.x + uu.y + uu.z + uu.w != 0.0f) {
            if (uu.x != 0.0f) { int p = atomicAdd(&s.nB, 1); if (p < CAP) s.idxB[p] = 4 * i;     }
            if (uu.y != 0.0f) { int p = atomicAdd(&s.nB, 1); if (p < CAP) s.idxB[p] = 4 * i + 1; }
            if (uu.z != 0.0f) { int p = atomicAdd(&s.nB, 1); if (p < CAP) s.idxB[p] = 4 * i + 2; }
            if (uu.w != 0.0f) { int p = atomicAdd(&s.nB, 1); if (p < CAP) s.idxB[p] = 4 * i + 3; }
        }
    }
    __syncthreads();
}

__device__ __forceinline__ void gather_tail(ScanSmem& s, int t, int pos,
    const float* __restrict__ gt, int transposed,
    const float* __restrict__ ft_b, const float* __restrict__ stm,
    const float* __restrict__ l1_w, const float* __restrict__ l1_b,
    const float* __restrict__ l2_w, const float* __restrict__ l2_b,
    const float* __restrict__ l3_w, const float* __restrict__ l3_b,
    float* __restrict__ out)
{
    const int cw = min(s.nW, CAP);
    const int cb = min(s.nB, CAP);

    float accW = ft_b[t];
    float accB = ft_b[t];
    if (transposed) {
        for (int j = 0; j < cw; ++j) accW += gt[(size_t)s.idxW[j] * MD + t];
        for (int j = 0; j < cb; ++j) accB += gt[(size_t)s.idxB[j] * MD + t];
    } else {
        const float* row = gt + (size_t)t * NF;
        for (int j = 0; j < cw; ++j) accW += row[s.idxW[j]];
        for (int j = 0; j < cb; ++j) accB += row[s.idxB[j]];
    }

    const float sv = stm[pos];
    s.xsh[t]       = clip01(sv * accW + (1.0f - sv) * accB);
    s.xsh[256 + t] = clip01(sv * accB + (1.0f - sv) * accW);
    __syncthreads();

    {
        const int n = t & 31;
        const int c = t >> 5;
        const float* w1 = l1_w + (size_t)n * 512 + c * 64;
        const float* xx = s.xsh + c * 64;
        float p = 0.0f;
        #pragma unroll
        for (int j = 0; j < 64; ++j) p += xx[j] * w1[j];
        s.red[n][c] = p;
    }
    __syncthreads();
    if (t < 32) {
        float v = l1_b[t];
        #pragma unroll
        for (int c = 0; c < 8; ++c) v += s.red[t][c];
        s.ysh[t] = clip01(v);
    }
    __syncthreads();
    if (t < 32) {
        float v = l2_b[t];
        const float* w2 = l2_w + t * 32;
        #pragma unroll
        for (int j = 0; j < 32; ++j) v += s.ysh[j] * w2[j];
        s.zsh[t] = clip01(v);
    }
    __syncthreads();
    if (t == 0) {
        float v = l3_b[0];
        #pragma unroll
        for (int j = 0; j < 32; ++j) v += s.zsh[j] * l3_w[j];
        out[pos] = (clip01(v) - 0.5f) * 20000.0f;
    }
}

__global__ __launch_bounds__(256) void transpose_ft(const float* __restrict__ in,
                                                    float* __restrict__ outT) {
    __shared__ float tile[64][65];
    const int b = blockIdx.x;
    const int f0 = (b % (NF / 64)) * 64;
    const int m0 = (b / (NF / 64)) * 64;
    const int tx = threadIdx.x & 63;
    const int ty = threadIdx.x >> 6;
    #pragma unroll
    for (int r = ty; r < 64; r += 4)
        tile[r][tx] = in[(size_t)(m0 + r) * NF + f0 + tx];
    __syncthreads();
    #pragma unroll
    for (int r = ty; r < 64; r += 4)
        outT[(size_t)(f0 + r) * MD + m0 + tx] = tile[tx][r];
}

__global__ __launch_bounds__(256) void nnue_plain(
    const float* __restrict__ wf, const float* __restrict__ bfeat,
    const float* __restrict__ stm, const float* __restrict__ gt,
    const float* __restrict__ ft_b,
    const float* __restrict__ l1_w, const float* __restrict__ l1_b,
    const float* __restrict__ l2_w, const float* __restrict__ l2_b,
    const float* __restrict__ l3_w, const float* __restrict__ l3_b,
    float* __restrict__ out, int transposed)
{
    __shared__ Smem u;
    const int pos = blockIdx.x;
    const int t = threadIdx.x;
    scan_pos(u.s, t, pos, wf, bfeat);
    gather_tail(u.s, t, pos, gt, transposed, ft_b, stm,
                l1_w, l1_b, l2_w, l2_b, l3_w, l3_b, out);
}

extern "C" void kernel_launch(void* const* d_in, const int* in_sizes, int n_in,
                              void* d_out, int out_size, void* d_ws, size_t ws_size,
                              hipStream_t stream) {
    const float* wf    = (const float*)d_in[0];
    const float* bfeat = (const float*)d_in[1];
    const float* stm   = (const float*)d_in[2];
    const float* ft_w  = (const float*)d_in[3];
    const float* ft_b  = (const float*)d_in[4];
    const float* l1_w  = (const float*)d_in[5];
    const float* l1_b  = (const float*)d_in[6];
    const float* l2_w  = (const float*)d_in[7];
    const float* l2_b  = (const float*)d_in[8];
    const float* l3_w  = (const float*)d_in[9];
    const float* l3_b  = (const float*)d_in[10];
    float* out = (float*)d_out;

    float* ftT = (float*)d_ws;
    const size_t needCoop = (size_t)(NF + 1) * MD * sizeof(float); // +1 zero pad row
    const size_t needT    = (size_t)NF * MD * sizeof(float);

    if (ws_size >= needCoop) {
        // host-side queries only (no stream ops) -> graph-capture safe
        int dev = 0, coopOK = 0, numCU = 0, maxBlk = 0;
        hipGetDevice(&dev);
        hipDeviceGetAttribute(&coopOK, hipDeviceAttributeCooperativeLaunch, dev);
        hipDeviceGetAttribute(&numCU, hipDeviceAttributeMultiprocessorCount, dev);
        hipOccupancyMaxActiveBlocksPerMultiprocessor(&maxBlk, nnue_coop2, 256, 0);
        if (coopOK && (long)maxBlk * numCU >= NBLK) {
            void* args[] = {
                (void*)&wf, (void*)&bfeat, (void*)&stm, (void*)&ft_w, (void*)&ft_b,
                (void*)&l1_w, (void*)&l1_b, (void*)&l2_w, (void*)&l2_b,
                (void*)&l3_w, (void*)&l3_b, (void*)&out, (void*)&ftT };
            hipError_t e = hipLaunchCooperativeKernel(
                (const void*)nnue_coop2, dim3(NBLK), dim3(256), args, 0, stream);
            if (e == hipSuccess) return;
        }
    }

    // fallback: verified two-kernel path
    if (ws_size >= needT) {
        transpose_ft<<<NTILE, 256, 0, stream>>>(ft_w, ftT);
        nnue_plain<<<BATCH, 256, 0, stream>>>(
            wf, bfeat, stm, ftT, ft_b,
            l1_w, l1_b, l2_w, l2_b, l3_w, l3_b, out, 1);
    } else {
        nnue_plain<<<BATCH, 256, 0, stream>>>(
            wf, bfeat, stm, ft_w, ft_b,
            l1_w, l1_b, l2_w, l2_b, l3_w, l3_b, out, 0);
    }
}

// Round 3
// 659.132 us; speedup vs baseline: 1.0508x; 1.0469x over previous
//
#include <hip/hip_runtime.h>
#include <hip/hip_bf16.h>

#define NF 40960
#define MD 256
#define BATCH 2048
#define CAP 512            // fallback path capacity
#define CAPB 128           // per-row index capacity (lambda=32, 17 sigma margin)
#define NTILE ((NF / 64) * (MD / 64))   // 2560 64x64 tiles
#define NROWS (2 * BATCH)               // 4096 (pos,color) rows

typedef float vf4 __attribute__((ext_vector_type(4)));
typedef unsigned int vu4 __attribute__((ext_vector_type(4)));

__device__ __forceinline__ float clip01(float v) {
    return fminf(fmaxf(v, 0.0f), 1.0f);
}

// ===========================================================================
// Kernel 1: transpose ft_w (M x F -> F x M) + zero pad row (index NF)
// ===========================================================================
__global__ __launch_bounds__(256) void transpose_ft(const float* __restrict__ in,
                                                    float* __restrict__ outT) {
    __shared__ float tile[64][65];
    const int b = blockIdx.x;
    const int t = threadIdx.x;
    if (b == 0) outT[(size_t)NF * MD + t] = 0.0f;   // zero pad row
    const int f0 = (b % (NF / 64)) * 64;
    const int m0 = (b / (NF / 64)) * 64;
    const int tx = t & 63;
    const int ty = t >> 6;
    #pragma unroll
    for (int r = ty; r < 64; r += 4)
        tile[r][tx] = in[(size_t)(m0 + r) * NF + f0 + tx];
    __syncthreads();
    #pragma unroll
    for (int r = ty; r < 64; r += 4)
        outT[(size_t)(f0 + r) * MD + m0 + tx] = tile[tx][r];
}

// ===========================================================================
// Kernel 2: branch-free streaming scan.
// Block g handles one contiguous 160KB row: color=g>>11, pos=g&2047.
// Hot loop: 40 independent uint4 loads -> 4-bit nibbles packed into 5 mask
// words per thread. No branches, no atomics, no LDS in the loop -> compiler
// can software-pipeline a deep vmcnt window (copy-kernel behavior).
// Emit phase walks the sparse masks (~12% of threads non-empty), compacts
// into LDS, then one coalesced flush per block. No global atomics.
// ===========================================================================
__global__ __launch_bounds__(256, 4) void nnue_scan(
    const float* __restrict__ wf, const float* __restrict__ bfeat,
    int* __restrict__ cnt, int* __restrict__ idxg)
{
    __shared__ int lidx[CAPB];
    __shared__ int lcnt;
    const int g = blockIdx.x;
    const int t = threadIdx.x;
    const int pos = g & (BATCH - 1);
    const int color = g >> 11;
    const int listId = g;   // white rows 0..2047, black rows 2048..4095

    if (t == 0) lcnt = 0;
    __syncthreads();

    const float* rowBase = (color ? bfeat : wf) + (size_t)pos * NF;
    const vu4* src = (const vu4*)rowBase;

    // ---- branch-free mask build: 40 loads/thread, bit29 of 0x3F800000 == 1
    unsigned int mask[5];
    #pragma unroll
    for (int w = 0; w < 5; ++w) {
        unsigned int acc = 0;
        #pragma unroll
        for (int q = 0; q < 8; ++q) {
            vu4 v = __builtin_nontemporal_load(src + t + (w * 8 + q) * 256);
            unsigned int nib = ((v.x >> 29) & 1u)
                             | (((v.y >> 29) & 1u) << 1)
                             | (((v.z >> 29) & 1u) << 2)
                             | (((v.w >> 29) & 1u) << 3);
            acc |= nib << (4 * q);
        }
        mask[w] = acc;
    }

    // ---- sparse emit (rare path)
    if (mask[0] | mask[1] | mask[2] | mask[3] | mask[4]) {
        #pragma unroll
        for (int w = 0; w < 5; ++w) {
            unsigned int x = mask[w];
            while (x) {
                const int b = __builtin_ctz(x);
                x &= x - 1;
                const int k = w * 8 + (b >> 2);       // which load
                const int fi = 4 * (t + k * 256) + (b & 3);
                const int p = atomicAdd(&lcnt, 1);
                if (p < CAPB) lidx[p] = fi;
            }
        }
    }
    __syncthreads();

    // ---- coalesced flush
    const int n = min(lcnt, CAPB);
    for (int j = t; j < n; j += 256) idxg[(size_t)listId * CAPB + j] = lidx[j];
    if (t == 0) cnt[listId] = n;
}

// ===========================================================================
// Kernel 3: batched gather from ftT (L3-resident) + MLP tail (verified R1).
// Lists padded to multiple of 8 with dummy index NF -> zero pad row, so the
// gather loop is mask-free with 16 independent loads in flight.
// ===========================================================================
struct GSmem {
    int iw[CAPB + 8], ib[CAPB + 8];
    float xsh[512];
    float red[32][9];
    float ysh[32], zsh[32];
};

__global__ __launch_bounds__(256, 4) void nnue_gather(
    const float* __restrict__ ftT,
    const int* __restrict__ cnt, const int* __restrict__ idxg,
    const float* __restrict__ ft_b, const float* __restrict__ stm,
    const float* __restrict__ l1_w, const float* __restrict__ l1_b,
    const float* __restrict__ l2_w, const float* __restrict__ l2_b,
    const float* __restrict__ l3_w, const float* __restrict__ l3_b,
    float* __restrict__ out)
{
    __shared__ GSmem s;
    const int pos = blockIdx.x;
    const int t = threadIdx.x;

    const int cw = min(cnt[pos], CAPB);
    const int cb = min(cnt[BATCH + pos], CAPB);
    const int m = (max(cw, cb) + 7) & ~7;

    for (int j = t; j < cw; j += 256) s.iw[j] = idxg[(size_t)pos * CAPB + j];
    for (int j = t; j < cb; j += 256) s.ib[j] = idxg[(size_t)(BATCH + pos) * CAPB + j];
    for (int j = cw + t; j < m; j += 256) s.iw[j] = NF;   // pad -> zero row
    for (int j = cb + t; j < m; j += 256) s.ib[j] = NF;
    __syncthreads();

    // ---- batched gather: 16 independent loads per iteration
    const float bias = ft_b[t];
    float aw = 0.0f, ab = 0.0f;
    for (int j = 0; j < m; j += 8) {
        float vw[8], vb[8];
        #pragma unroll
        for (int q = 0; q < 8; ++q) vw[q] = ftT[(size_t)s.iw[j + q] * MD + t];
        #pragma unroll
        for (int q = 0; q < 8; ++q) vb[q] = ftT[(size_t)s.ib[j + q] * MD + t];
        aw += ((vw[0] + vw[1]) + (vw[2] + vw[3])) + ((vw[4] + vw[5]) + (vw[6] + vw[7]));
        ab += ((vb[0] + vb[1]) + (vb[2] + vb[3])) + ((vb[4] + vb[5]) + (vb[6] + vb[7]));
    }
    const float accW = bias + aw;
    const float accB = bias + ab;

    // ---- verified MLP tail
    const float sv = stm[pos];
    s.xsh[t]       = clip01(sv * accW + (1.0f - sv) * accB);
    s.xsh[256 + t] = clip01(sv * accB + (1.0f - sv) * accW);
    __syncthreads();
    {   // L1: n = t&31 (broadcast reads), chunk c = t>>5
        const int n = t & 31;
        const int c = t >> 5;
        const float* w1 = l1_w + (size_t)n * 512 + c * 64;
        const float* xx = s.xsh + c * 64;
        float p = 0.0f;
        #pragma unroll
        for (int j = 0; j < 64; ++j) p += xx[j] * w1[j];
        s.red[n][c] = p;
    }
    __syncthreads();
    if (t < 32) {
        float v = l1_b[t];
        #pragma unroll
        for (int c = 0; c < 8; ++c) v += s.red[t][c];
        s.ysh[t] = clip01(v);
    }
    __syncthreads();
    if (t < 32) {
        float v = l2_b[t];
        const float* w2 = l2_w + t * 32;
        #pragma unroll
        for (int j = 0; j < 32; ++j) v += s.ysh[j] * w2[j];
        s.zsh[t] = clip01(v);
    }
    __syncthreads();
    if (t == 0) {
        float v = l3_b[0];
        #pragma unroll
        for (int j = 0; j < 32; ++j) v += s.zsh[j] * l3_w[j];
        out[pos] = (clip01(v) - 0.5f) * 20000.0f;
    }
}

// ===========================================================================
// Fallback path (verified R1): separate transpose + monolithic kernel.
// ===========================================================================
struct ScanSmem {
    int idxW[CAP], idxB[CAP];
    int nW, nB;
    float xsh[512];
    float red[32][9];
    float ysh[32], zsh[32];
};
union Smem {
    float tile[64][65];
    ScanSmem s;
};

__device__ __forceinline__ void scan_pos(ScanSmem& s, int t, int pos,
    const float* __restrict__ wf, const float* __restrict__ bfeat)
{
    if (t == 0) { s.nW = 0; s.nB = 0; }
    __syncthreads();
    const vf4* wf4 = (const vf4*)(wf + (size_t)pos * NF);
    const vf4* bf4 = (const vf4*)(bfeat + (size_t)pos * NF);
    #pragma unroll 4
    for (int i = t; i < NF / 4; i += 256) {
        vf4 v = __builtin_nontemporal_load(wf4 + i);
        if (v.x + v.y + v.z + v.w != 0.0f) {
            if (v.x != 0.0f) { int p = atomicAdd(&s.nW, 1); if (p < CAP) s.idxW[p] = 4 * i;     }
            if (v.y != 0.0f) { int p = atomicAdd(&s.nW, 1); if (p < CAP) s.idxW[p] = 4 * i + 1; }
            if (v.z != 0.0f) { int p = atomicAdd(&s.nW, 1); if (p < CAP) s.idxW[p] = 4 * i + 2; }
            if (v.w != 0.0f) { int p = atomicAdd(&s.nW, 1); if (p < CAP) s.idxW[p] = 4 * i + 3; }
        }
        vf4 uu = __builtin_nontemporal_load(bf4 + i);
        if (uu.x + uu.y + uu.z + uu.w != 0.0f) {
            if (uu.x != 0.0f) { int p = atomicAdd(&s.nB, 1); if (p < CAP) s.idxB[p] = 4 * i;     }
            if (uu.y != 0.0f) { int p = atomicAdd(&s.nB, 1); if (p < CAP) s.idxB[p] = 4 * i + 1; }
            if (uu.z != 0.0f) { int p = atomicAdd(&s.nB, 1); if (p < CAP) s.idxB[p] = 4 * i + 2; }
            if (uu.w != 0.0f) { int p = atomicAdd(&s.nB, 1); if (p < CAP) s.idxB[p] = 4 * i + 3; }
        }
    }
    __syncthreads();
}

__device__ __forceinline__ void gather_tail(ScanSmem& s, int t, int pos,
    const float* __restrict__ gt, int transposed,
    const float* __restrict__ ft_b, const float* __restrict__ stm,
    const float* __restrict__ l1_w, const float* __restrict__ l1_b,
    const float* __restrict__ l2_w, const float* __restrict__ l2_b,
    const float* __restrict__ l3_w, const float* __restrict__ l3_b,
    float* __restrict__ out)
{
    const int cw = min(s.nW, CAP);
    const int cb = min(s.nB, CAP);

    float accW = ft_b[t];
    float accB = ft_b[t];
    if (transposed) {
        for (int j = 0; j < cw; ++j) accW += gt[(size_t)s.idxW[j] * MD + t];
        for (int j = 0; j < cb; ++j) accB += gt[(size_t)s.idxB[j] * MD + t];
    } else {
        const float* row = gt + (size_t)t * NF;
        for (int j = 0; j < cw; ++j) accW += row[s.idxW[j]];
        for (int j = 0; j < cb; ++j) accB += row[s.idxB[j]];
    }

    const float sv = stm[pos];
    s.xsh[t]       = clip01(sv * accW + (1.0f - sv) * accB);
    s.xsh[256 + t] = clip01(sv * accB + (1.0f - sv) * accW);
    __syncthreads();

    {
        const int n = t & 31;
        const int c = t >> 5;
        const float* w1 = l1_w + (size_t)n * 512 + c * 64;
        const float* xx = s.xsh + c * 64;
        float p = 0.0f;
        #pragma unroll
        for (int j = 0; j < 64; ++j) p += xx[j] * w1[j];
        s.red[n][c] = p;
    }
    __syncthreads();
    if (t < 32) {
        float v = l1_b[t];
        #pragma unroll
        for (int c = 0; c < 8; ++c) v += s.red[t][c];
        s.ysh[t] = clip01(v);
    }
    __syncthreads();
    if (t < 32) {
        float v = l2_b[t];
        const float* w2 = l2_w + t * 32;
        #pragma unroll
        for (int j = 0; j < 32; ++j) v += s.ysh[j] * w2[j];
        s.zsh[t] = clip01(v);
    }
    __syncthreads();
    if (t == 0) {
        float v = l3_b[0];
        #pragma unroll
        for (int j = 0; j < 32; ++j) v += s.zsh[j] * l3_w[j];
        out[pos] = (clip01(v) - 0.5f) * 20000.0f;
    }
}

__global__ __launch_bounds__(256) void nnue_plain(
    const float* __restrict__ wf, const float* __restrict__ bfeat,
    const float* __restrict__ stm, const float* __restrict__ gt,
    const float* __restrict__ ft_b,
    const float* __restrict__ l1_w, const float* __restrict__ l1_b,
    const float* __restrict__ l2_w, const float* __restrict__ l2_b,
    const float* __restrict__ l3_w, const float* __restrict__ l3_b,
    float* __restrict__ out, int transposed)
{
    __shared__ Smem u;
    const int pos = blockIdx.x;
    const int t = threadIdx.x;
    scan_pos(u.s, t, pos, wf, bfeat);
    gather_tail(u.s, t, pos, gt, transposed, ft_b, stm,
                l1_w, l1_b, l2_w, l2_b, l3_w, l3_b, out);
}

extern "C" void kernel_launch(void* const* d_in, const int* in_sizes, int n_in,
                              void* d_out, int out_size, void* d_ws, size_t ws_size,
                              hipStream_t stream) {
    const float* wf    = (const float*)d_in[0];
    const float* bfeat = (const float*)d_in[1];
    const float* stm   = (const float*)d_in[2];
    const float* ft_w  = (const float*)d_in[3];
    const float* ft_b  = (const float*)d_in[4];
    const float* l1_w  = (const float*)d_in[5];
    const float* l1_b  = (const float*)d_in[6];
    const float* l2_w  = (const float*)d_in[7];
    const float* l2_b  = (const float*)d_in[8];
    const float* l3_w  = (const float*)d_in[9];
    const float* l3_b  = (const float*)d_in[10];
    float* out = (float*)d_out;

    // workspace layout: ftT[(NF+1)*MD] | cnt[NROWS] | idxg[NROWS*CAPB]
    float* ftT = (float*)d_ws;
    int* cnt  = (int*)((float*)d_ws + (size_t)(NF + 1) * MD);
    int* idxg = cnt + NROWS;
    const size_t needFull = (size_t)(NF + 1) * MD * sizeof(float)
                          + (size_t)NROWS * sizeof(int)
                          + (size_t)NROWS * CAPB * sizeof(int);
    const size_t needT = (size_t)NF * MD * sizeof(float);

    if (ws_size >= needFull) {
        // fast path: 3 plain dispatches, graph-capture safe, no host queries
        transpose_ft<<<NTILE, 256, 0, stream>>>(ft_w, ftT);
        nnue_scan<<<NROWS, 256, 0, stream>>>(wf, bfeat, cnt, idxg);
        nnue_gather<<<BATCH, 256, 0, stream>>>(
            ftT, cnt, idxg, ft_b, stm,
            l1_w, l1_b, l2_w, l2_b, l3_w, l3_b, out);
        return;
    }

    // fallback: verified two-kernel path
    if (ws_size >= needT) {
        transpose_ft<<<NTILE, 256, 0, stream>>>(ft_w, ftT);
        nnue_plain<<<BATCH, 256, 0, stream>>>(
            wf, bfeat, stm, ftT, ft_b,
            l1_w, l1_b, l2_w, l2_b, l3_w, l3_b, out, 1);
    } else {
        nnue_plain<<<BATCH, 256, 0, stream>>>(
            wf, bfeat, stm, ft_w, ft_b,
            l1_w, l1_b, l2_w, l2_b, l3_w, l3_b, out, 0);
    }
}